// Round 5
// baseline (162.784 us; speedup 1.0000x reference)
//
#include <hip/hip_runtime.h>
#include <hip/hip_bf16.h>
#include <math.h>

// QuantumFFN: out[m,n] = sum_k relu(sum_q cos(x[m,q])cos(theta[q]) * W1[k,q]) * W2[n,k]
// M=16384, N=1024, K=4096, Q=8.
//
// Pass 1 (k_prep): h (bf16, XOR-swizzled tiles) and W2 (bf16, linear tiles) -> d_ws.
// Pass 2 (k_gemm): 256x256 bf16 MFMA GEMM, BK=32.
//   A: global_load_lds -> 4-deep LDS ring -> swizzled ds_read_b128 fragments.
//   B: DIRECT global->register loads (L2-resident 2 MB slice), double-buffered.
//   LDS traffic per tile drops 128KB -> 80KB; MFMA pipe becomes critical path.

using f32x4  = __attribute__((ext_vector_type(4))) float;
using bf16x8 = __attribute__((ext_vector_type(8))) short;
using i32x4  = __attribute__((ext_vector_type(4))) int;

#define M_TOT 16384
#define N_TOT 1024
#define K_TOT 4096
#define NKT   128        // K-tiles of 32
#define TILEB 16384      // 256 rows x 32 k x 2B

static const size_t H_BYTES   = (size_t)M_TOT * K_TOT * 2;   // 128 MiB
static const size_t W2B_BYTES = (size_t)N_TOT * K_TOT * 2;   //   8 MiB
static const size_t WS_NEED   = H_BYTES + W2B_BYTES;

// swizzle within a 64-byte tile row (4 slots of 16B): slot' = slot ^ ((row>>1)&3)
#define SWZ32(row, bytecol) ((bytecol) ^ ((((row) >> 1) & 3) << 4))

#define GLD16(gp, lp) __builtin_amdgcn_global_load_lds( \
    (const __attribute__((address_space(1))) unsigned int*)(const void*)(gp), \
    (__attribute__((address_space(3))) unsigned int*)(void*)(lp), 16, 0, 0)

static __device__ inline unsigned short f2bf(float f) {
    __hip_bfloat16 b = __float2bfloat16(f);
    unsigned short u;
    __builtin_memcpy(&u, &b, 2);
    return u;
}

// ---------------- pass 1: h (swizzled) and W2 (linear) -> bf16 tiled ----------------
// blocks 0..2047: h path (bx = b>>5 m-tile of 256, by = b&31 k-chunk of 128)
// blocks 2048..4095: w2 convert path
__global__ __launch_bounds__(256)
void k_prep(const float* __restrict__ x, const float* __restrict__ theta,
            const float* __restrict__ W1, const float* __restrict__ W2,
            char* __restrict__ hws, char* __restrict__ w2ws)
{
    __shared__ float sZ[256 * 8];
    __shared__ float sW[128 * 8];
    const int tid = threadIdx.x;

    if (blockIdx.x < 2048) {
        const int bx = blockIdx.x >> 5;
        const int by = blockIdx.x & 31;

        {   // z for this block's 256 rows (one row per thread)
            const float* xp = x + ((size_t)bx * 256 + tid) * 1024;
            f32x4 a = *reinterpret_cast<const f32x4*>(xp);
            f32x4 b = *reinterpret_cast<const f32x4*>(xp + 4);
            #pragma unroll
            for (int q = 0; q < 4; ++q) {
                sZ[tid * 8 + q]     = cosf(a[q]) * cosf(theta[q]);
                sZ[tid * 8 + 4 + q] = cosf(b[q]) * cosf(theta[q + 4]);
            }
        }
        *reinterpret_cast<f32x4*>(&sW[tid * 4]) =
            *reinterpret_cast<const f32x4*>(W1 + (size_t)by * 1024 + tid * 4);
        __syncthreads();

        const int tm = tid >> 4;     // rows tm*16..+15
        const int tk = tid & 15;     // k-cols tk*8..+7 (within 128-chunk)

        f32x4 wA[8], wB[8];
        #pragma unroll
        for (int kk = 0; kk < 8; ++kk) {
            wA[kk] = *reinterpret_cast<const f32x4*>(&sW[(tk * 8 + kk) * 8]);
            wB[kk] = *reinterpret_cast<const f32x4*>(&sW[(tk * 8 + kk) * 8 + 4]);
        }

        const int kt    = by * 4 + (tk >> 2);
        const int slotb = (tk & 3) * 16;
        char* tb = hws + ((size_t)bx * NKT + kt) * TILEB;

        #pragma unroll
        for (int i = 0; i < 16; ++i) {
            const int row = tm * 16 + i;
            f32x4 za = *reinterpret_cast<const f32x4*>(&sZ[row * 8]);
            f32x4 zb = *reinterpret_cast<const f32x4*>(&sZ[row * 8 + 4]);
            unsigned hu[8];
            #pragma unroll
            for (int kk = 0; kk < 8; ++kk) {
                float h = 0.f;
                #pragma unroll
                for (int q = 0; q < 4; ++q) {
                    h = fmaf(za[q], wA[kk][q], h);
                    h = fmaf(zb[q], wB[kk][q], h);
                }
                hu[kk] = (unsigned)f2bf(fmaxf(h, 0.f));
            }
            i32x4 pk;
            pk[0] = (int)(hu[0] | (hu[1] << 16));
            pk[1] = (int)(hu[2] | (hu[3] << 16));
            pk[2] = (int)(hu[4] | (hu[5] << 16));
            pk[3] = (int)(hu[6] | (hu[7] << 16));
            *reinterpret_cast<i32x4*>(tb + row * 64 + SWZ32(row, slotb)) = pk;
        }
    } else {
        const int gt = (blockIdx.x - 2048) * 256 + tid;  // one 8-k unit each
        const int n  = gt >> 9;                          // 512 units per n-row
        const int k8 = gt & 511;
        const float* p = W2 + (size_t)n * K_TOT + k8 * 8;
        f32x4 a = *reinterpret_cast<const f32x4*>(p);
        f32x4 b = *reinterpret_cast<const f32x4*>(p + 4);
        i32x4 pk;
        pk[0] = (int)((unsigned)f2bf(a[0]) | ((unsigned)f2bf(a[1]) << 16));
        pk[1] = (int)((unsigned)f2bf(a[2]) | ((unsigned)f2bf(a[3]) << 16));
        pk[2] = (int)((unsigned)f2bf(b[0]) | ((unsigned)f2bf(b[1]) << 16));
        pk[3] = (int)((unsigned)f2bf(b[2]) | ((unsigned)f2bf(b[3]) << 16));
        // linear layout (no swizzle): [nt][kt][row 256][32 k]
        const int nt = n >> 8, row = n & 255, kt = k8 >> 2, slotb = (k8 & 3) * 16;
        char* dst = w2ws + ((size_t)nt * NKT + kt) * TILEB + row * 64 + slotb;
        *reinterpret_cast<i32x4*>(dst) = pk;
    }
}

// ---------------- pass 2: out = h @ W2^T ----------------
// 256x256 block tile, BK=32, 8 waves (2Mx4N, 128x64 per wave).
// A: 4-deep LDS ring (64 KB), staged 3 tiles ahead. B: direct global->reg, 1 ahead.

#define DS_FRAGS(RD, BUF1) do {                                                   \
    const char* sa_ = ldsA + (BUF1) * 16384;                                      \
    _Pragma("unroll")                                                             \
    for (int i = 0; i < 8; ++i)                                                   \
        Pa[RD][i] = *reinterpret_cast<const bf16x8*>(sa_ + aoff + i * 1024);      \
} while (0)

#define B_LOAD(RD, KT1) do {                                                      \
    const char* gb_ = bT + (size_t)(KT1) * TILEB + bofsG;                         \
    _Pragma("unroll")                                                             \
    for (int j = 0; j < 4; ++j)                                                   \
        Pb[RD][j] = *reinterpret_cast<const bf16x8*>(gb_ + j * 1024);             \
} while (0)

#define STAGE2(KT3, BUF3) do {                                                    \
    const char* ga_ = aT + (size_t)(KT3) * TILEB;                                 \
    GLD16(ga_ + gofs,        ldsA + (BUF3) * 16384 + lofs);                       \
    GLD16(ga_ + 8192 + gofs, ldsA + (BUF3) * 16384 + 8192 + lofs);                \
} while (0)

#define MFMA32(USE) do {                                                          \
    __builtin_amdgcn_s_setprio(1);                                                \
    _Pragma("unroll")                                                             \
    for (int i = 0; i < 8; ++i)                                                   \
        _Pragma("unroll")                                                         \
        for (int j = 0; j < 4; ++j)                                               \
            acc[i][j] = __builtin_amdgcn_mfma_f32_16x16x32_bf16(Pa[USE][i], Pb[USE][j], acc[i][j], 0, 0, 0); \
    __builtin_amdgcn_s_setprio(0);                                                \
} while (0)

#define PHASE(BUF, KT, WN, DOB, DOSTAGE) do {                                     \
    asm volatile("s_waitcnt vmcnt(" #WN ")" ::: "memory");                        \
    __builtin_amdgcn_sched_barrier(0);                                            \
    __builtin_amdgcn_s_barrier();                                                 \
    __builtin_amdgcn_sched_barrier(0);                                            \
    DS_FRAGS(((BUF) + 1) & 1, ((BUF) + 1) & 3);                                   \
    if (DOB)     B_LOAD(((BUF) + 1) & 1, (KT) + 1);                               \
    if (DOSTAGE) STAGE2((KT) + 3, ((BUF) + 3) & 3);                               \
    __builtin_amdgcn_sched_barrier(0);                                            \
    MFMA32((BUF) & 1);                                                            \
} while (0)

__global__ __launch_bounds__(512, 2)
void k_gemm(const char* __restrict__ hws, const char* __restrict__ w2ws,
            float* __restrict__ out)
{
    __shared__ __align__(16) char ldsA[65536];   // 4 x 16 KB A ring

    const int tid  = threadIdx.x;
    const int lane = tid & 63;
    const int wave = tid >> 6;
    const int wm = wave >> 2;        // 0..1
    const int wn = wave & 3;         // 0..3
    const int mt = blockIdx.x;       // 0..63
    const int nt = blockIdx.y;       // 0..3

    const char* aT = hws  + (size_t)mt * NKT * TILEB;
    const char* bT = w2ws + (size_t)nt * NKT * TILEB;

    const int l16 = lane & 15;
    const int lkb = (lane >> 4) * 16;
    // A frag LDS offsets: +i*1024 preserves row&7 (16-row step) -> swizzle-invariant
    const int arow0 = wm * 128 + l16;
    const int aoff  = arow0 * 64 + SWZ32(arow0, lkb);
    // B frag global offset within a tile: row = wn*64 + j*16 + l16, byte = row*64 + (lane>>4)*16
    const int bofsG = wn * 4096 + l16 * 64 + (lane >> 4) * 16;

    const int gofs = tid * 16;
    const int lofs = wave * 1024;

    bf16x8 Pa[2][8];
    bf16x8 Pb[2][4];

    f32x4 acc[8][4];
    #pragma unroll
    for (int i = 0; i < 8; ++i)
        #pragma unroll
        for (int j = 0; j < 4; ++j)
            acc[i][j] = {0.f, 0.f, 0.f, 0.f};

    // prologue: stage A tiles 0,1,2 (6 GLD); load B(0) (4 loads)
    STAGE2(0, 0);
    STAGE2(1, 1);
    STAGE2(2, 2);
    B_LOAD(0, 0);
    asm volatile("s_waitcnt vmcnt(8)" ::: "memory");   // A tile 0 resident
    __builtin_amdgcn_sched_barrier(0);
    __builtin_amdgcn_s_barrier();
    __builtin_amdgcn_sched_barrier(0);
    DS_FRAGS(0, 0);

    #pragma unroll 1
    for (int t = 0; t < 124; t += 4) {
        PHASE(0, t,     6, 1, 1);
        PHASE(1, t + 1, 6, 1, 1);
        PHASE(2, t + 2, 6, 1, 1);
        PHASE(3, t + 3, 6, 1, 1);
    }
    PHASE(0, 124, 6, 1, 1);   // stages A tile 127
    PHASE(1, 125, 6, 1, 0);
    PHASE(2, 126, 4, 1, 0);   // reads frag 127, loads B(127)
    __builtin_amdgcn_sched_barrier(0);
    MFMA32(1);                // tile 127 (compiler waits vmcnt for B(127))

    const int orow0 = mt * 256 + wm * 128 + (lane >> 4) * 4;
    const int ocol0 = nt * 256 + wn * 64 + l16;
    #pragma unroll
    for (int i = 0; i < 8; ++i)
        #pragma unroll
        for (int j = 0; j < 4; ++j)
            #pragma unroll
            for (int jj = 0; jj < 4; ++jj)
                out[(size_t)(orow0 + i * 16 + jj) * N_TOT + (ocol0 + j * 16)] = acc[i][j][jj];
}

// ---------------- fallback: fused single kernel (ws too small) ----------------
__global__ __launch_bounds__(256, 3)
void qffn_fused(const float* __restrict__ x, const float* __restrict__ theta,
                const float* __restrict__ W1, const float* __restrict__ W2,
                float* __restrict__ out)
{
    __shared__ __align__(16) unsigned short sA[128 * 64];
    __shared__ __align__(16) unsigned short sB[128 * 64];

    const int tid  = threadIdx.x;
    const int lane = tid & 63;
    const int wave = tid >> 6;
    const int m0 = blockIdx.x * 128;
    const int n0 = blockIdx.y * 128;

    const int arow = tid & 127;
    float zc[8];
    {
        const float* xp = x + (size_t)(m0 + arow) * 1024;
        f32x4 x0 = *reinterpret_cast<const f32x4*>(xp);
        f32x4 x1 = *reinterpret_cast<const f32x4*>(xp + 4);
        #pragma unroll
        for (int q = 0; q < 4; ++q) {
            zc[q]     = cosf(x0[q]) * cosf(theta[q]);
            zc[q + 4] = cosf(x1[q]) * cosf(theta[q + 4]);
        }
    }

    f32x4 acc[4][4];
    #pragma unroll
    for (int i = 0; i < 4; ++i)
        #pragma unroll
        for (int j = 0; j < 4; ++j)
            acc[i][j] = {0.f, 0.f, 0.f, 0.f};

    const int wr  = (wave >> 1) * 64;
    const int wc  = (wave & 1) * 64;
    const int l16 = lane & 15;
    const int lk8 = (lane >> 4) * 8;

    for (int k0 = 0; k0 < K_TOT; k0 += 64) {
        #pragma unroll
        for (int g = 0; g < 4; ++g) {
            const int cg  = (tid >> 7) + 2 * g;
            const int cgu = __builtin_amdgcn_readfirstlane(cg);
            const float* w1p = W1 + (size_t)(k0 + cgu * 8) * 8;
            i32x4 pk;
            #pragma unroll
            for (int p = 0; p < 4; ++p) {
                float h0 = 0.f, h1 = 0.f;
                #pragma unroll
                for (int q = 0; q < 8; ++q) {
                    h0 = fmaf(zc[q], w1p[(2 * p) * 8 + q], h0);
                    h1 = fmaf(zc[q], w1p[(2 * p + 1) * 8 + q], h1);
                }
                pk[p] = (int)(((unsigned)f2bf(fmaxf(h0, 0.f))) |
                              (((unsigned)f2bf(fmaxf(h1, 0.f))) << 16));
            }
            const int off = (arow * 64 + cg * 8) ^ ((arow & 7) << 3);
            *reinterpret_cast<i32x4*>(&sA[off]) = pk;
        }
        {
            const int fi = tid & 15;
            const int rb = tid >> 4;
            #pragma unroll
            for (int r = 0; r < 8; ++r) {
                const int row = rb + r * 16;
                f32x4 v = *(reinterpret_cast<const f32x4*>(W2 + (size_t)(n0 + row) * K_TOT + k0) + fi);
                unsigned p0 = (unsigned)f2bf(v[0]) | ((unsigned)f2bf(v[1]) << 16);
                unsigned p1 = (unsigned)f2bf(v[2]) | ((unsigned)f2bf(v[3]) << 16);
                const int off = (row * 64 + fi * 4) ^ ((row & 7) << 3);
                *reinterpret_cast<unsigned*>(&sB[off])     = p0;
                *reinterpret_cast<unsigned*>(&sB[off + 2]) = p1;
            }
        }
        __syncthreads();

        #pragma unroll
        for (int s = 0; s < 2; ++s) {
            bf16x8 af[4], bfr[4];
            #pragma unroll
            for (int i = 0; i < 4; ++i) {
                const int row = wr + i * 16 + l16;
                const int off = (row * 64 + s * 32 + lk8) ^ ((row & 7) << 3);
                af[i] = *reinterpret_cast<const bf16x8*>(&sA[off]);
            }
            #pragma unroll
            for (int j = 0; j < 4; ++j) {
                const int row = wc + j * 16 + l16;
                const int off = (row * 64 + s * 32 + lk8) ^ ((row & 7) << 3);
                bfr[j] = *reinterpret_cast<const bf16x8*>(&sB[off]);
            }
            #pragma unroll
            for (int i = 0; i < 4; ++i)
                #pragma unroll
                for (int j = 0; j < 4; ++j)
                    acc[i][j] = __builtin_amdgcn_mfma_f32_16x16x32_bf16(af[i], bfr[j], acc[i][j], 0, 0, 0);
        }
        __syncthreads();
    }

    const int orow0 = m0 + wr + (lane >> 4) * 4;
    const int ocol0 = n0 + wc + l16;
    #pragma unroll
    for (int i = 0; i < 4; ++i)
        #pragma unroll
        for (int j = 0; j < 4; ++j)
            #pragma unroll
            for (int jj = 0; jj < 4; ++jj)
                out[(size_t)(orow0 + i * 16 + jj) * N_TOT + (ocol0 + j * 16)] = acc[i][j][jj];
}

extern "C" void kernel_launch(void* const* d_in, const int* in_sizes, int n_in,
                              void* d_out, int out_size, void* d_ws, size_t ws_size,
                              hipStream_t stream) {
    const float* x     = (const float*)d_in[0];
    const float* theta = (const float*)d_in[1];
    const float* W1    = (const float*)d_in[2];
    const float* W2    = (const float*)d_in[3];
    float* out = (float*)d_out;

    if (ws_size >= WS_NEED) {
        char* hws  = (char*)d_ws;
        char* w2ws = (char*)d_ws + H_BYTES;

        k_prep<<<dim3(4096), dim3(256), 0, stream>>>(x, theta, W1, W2, hws, w2ws);
        k_gemm<<<dim3(M_TOT / 256, N_TOT / 256), dim3(512), 0, stream>>>(hws, w2ws, out);
    } else {
        qffn_fused<<<dim3(M_TOT / 128, N_TOT / 128), dim3(256), 0, stream>>>(x, theta, W1, W2, out);
    }
}

// Round 6
// 140.539 us; speedup vs baseline: 1.1583x; 1.1583x over previous
//
#include <hip/hip_runtime.h>
#include <hip/hip_bf16.h>
#include <math.h>

// QuantumFFN: out[m,n] = sum_k relu(sum_q cos(x[m,q])cos(theta[q]) * W1[k,q]) * W2[n,k]
// M=16384, N=1024, K=4096, Q=8.
//
// Pass 1 (k_prep): h (bf16) and W2 (bf16) -> d_ws, half-tile-linear layout with
//   inverse XOR-swizzle applied at the producer (so global_load_lds linear dest +
//   swizzled ds_read works; rule "both-sides-or-neither").
// Pass 2 (k_gemm): m201-style 8-phase 256x256 BK=64 schedule:
//   2 K-tiles/iter, 8 phases; per phase {ds_reads; stage 1 half-tile (2 GLD);
//   barrier; lgkmcnt(0); 16 MFMA w/ setprio}; vmcnt(4) only at phases 4 and 8.

using f32x4  = __attribute__((ext_vector_type(4))) float;
using bf16x8 = __attribute__((ext_vector_type(8))) short;
using i32x4  = __attribute__((ext_vector_type(4))) int;

#define M_TOT 16384
#define N_TOT 1024
#define K_TOT 4096
#define NKT   64         // K-tiles of 64
#define HTB   16384      // half-tile bytes: 128 rows x 64 k x 2B

static const size_t H_BYTES   = (size_t)M_TOT * K_TOT * 2;   // 128 MiB
static const size_t W2B_BYTES = (size_t)N_TOT * K_TOT * 2;   //   8 MiB
static const size_t WS_NEED   = H_BYTES + W2B_BYTES;

// swizzle within a 128-byte row (8 slots of 16B): byte ^= (row&7)<<4
#define SWZ(row, bytecol) ((bytecol) ^ (((row) & 7) << 4))

#define GLD16(gp, lp) __builtin_amdgcn_global_load_lds( \
    (const __attribute__((address_space(1))) unsigned int*)(const void*)(gp), \
    (__attribute__((address_space(3))) unsigned int*)(void*)(lp), 16, 0, 0)

static __device__ inline unsigned short f2bf(float f) {
    __hip_bfloat16 b = __float2bfloat16(f);
    unsigned short u;
    __builtin_memcpy(&u, &b, 2);
    return u;
}

// ---------------- pass 1: h and W2 -> bf16 half-tile-linear, pre-swizzled ----------------
// blocks 0..2047: h path (bx = b>>5 m-tile of 256, by = b&31 k-chunk of 128 = 2 K-tiles)
// blocks 2048..4095: w2 convert path
__global__ __launch_bounds__(256)
void k_prep(const float* __restrict__ x, const float* __restrict__ theta,
            const float* __restrict__ W1, const float* __restrict__ W2,
            char* __restrict__ hws, char* __restrict__ w2ws)
{
    __shared__ float sZ[256 * 8];
    __shared__ float sW[128 * 8];
    const int tid = threadIdx.x;

    if (blockIdx.x < 2048) {
        const int bx = blockIdx.x >> 5;
        const int by = blockIdx.x & 31;

        {   // z for this block's 256 rows (one row per thread)
            const float* xp = x + ((size_t)bx * 256 + tid) * 1024;
            f32x4 a = *reinterpret_cast<const f32x4*>(xp);
            f32x4 b = *reinterpret_cast<const f32x4*>(xp + 4);
            #pragma unroll
            for (int q = 0; q < 4; ++q) {
                sZ[tid * 8 + q]     = cosf(a[q]) * cosf(theta[q]);
                sZ[tid * 8 + 4 + q] = cosf(b[q]) * cosf(theta[q + 4]);
            }
        }
        *reinterpret_cast<f32x4*>(&sW[tid * 4]) =
            *reinterpret_cast<const f32x4*>(W1 + (size_t)by * 1024 + tid * 4);
        __syncthreads();

        const int tm = tid >> 4;     // rows tm*16..+15
        const int tk = tid & 15;     // k-cols tk*8..+7 (within 128-chunk)

        f32x4 wA[8], wB[8];
        #pragma unroll
        for (int kk = 0; kk < 8; ++kk) {
            wA[kk] = *reinterpret_cast<const f32x4*>(&sW[(tk * 8 + kk) * 8]);
            wB[kk] = *reinterpret_cast<const f32x4*>(&sW[(tk * 8 + kk) * 8 + 4]);
        }

        const int kt    = by * 2 + (tk >> 3);    // global K-tile (64 k each)
        const int slotb = (tk & 7) * 16;         // byte col within 128-B row

        #pragma unroll
        for (int i = 0; i < 16; ++i) {
            const int R = tm * 16 + i;           // 0..255
            f32x4 za = *reinterpret_cast<const f32x4*>(&sZ[R * 8]);
            f32x4 zb = *reinterpret_cast<const f32x4*>(&sZ[R * 8 + 4]);
            unsigned hu[8];
            #pragma unroll
            for (int kk = 0; kk < 8; ++kk) {
                float h = 0.f;
                #pragma unroll
                for (int q = 0; q < 4; ++q) {
                    h = fmaf(za[q], wA[kk][q], h);
                    h = fmaf(zb[q], wB[kk][q], h);
                }
                hu[kk] = (unsigned)f2bf(fmaxf(h, 0.f));
            }
            i32x4 pk;
            pk[0] = (int)(hu[0] | (hu[1] << 16));
            pk[1] = (int)(hu[2] | (hu[3] << 16));
            pk[2] = (int)(hu[4] | (hu[5] << 16));
            pk[3] = (int)(hu[6] | (hu[7] << 16));
            char* dst = hws + ((size_t)((bx * NKT + kt) * 2 + (R >> 7))) * HTB
                      + (size_t)(R & 127) * 128 + SWZ(R, slotb);
            *reinterpret_cast<i32x4*>(dst) = pk;
        }
    } else {
        const int gt = (blockIdx.x - 2048) * 256 + tid;  // one 8-k (16B) unit each
        const int n  = gt >> 9;                          // 512 units per n-row
        const int k8 = gt & 511;
        const float* p = W2 + (size_t)n * K_TOT + k8 * 8;
        f32x4 a = *reinterpret_cast<const f32x4*>(p);
        f32x4 b = *reinterpret_cast<const f32x4*>(p + 4);
        i32x4 pk;
        pk[0] = (int)((unsigned)f2bf(a[0]) | ((unsigned)f2bf(a[1]) << 16));
        pk[1] = (int)((unsigned)f2bf(a[2]) | ((unsigned)f2bf(a[3]) << 16));
        pk[2] = (int)((unsigned)f2bf(b[0]) | ((unsigned)f2bf(b[1]) << 16));
        pk[3] = (int)((unsigned)f2bf(b[2]) | ((unsigned)f2bf(b[3]) << 16));
        const int nt = n >> 8, R = n & 255, kt = k8 >> 3, slotb = (k8 & 7) * 16;
        char* dst = w2ws + ((size_t)((nt * NKT + kt) * 2 + (R >> 7))) * HTB
                  + (size_t)(R & 127) * 128 + SWZ(R, slotb);
        *reinterpret_cast<i32x4*>(dst) = pk;
    }
}

// ---------------- pass 2: out = h @ W2^T, 8-phase schedule ----------------
// LDS map (128 KiB): buf d in [d*65536, d*65536+65536):
//   A half h: d*65536 + h*16384 ; B half h: d*65536 + 32768 + h*16384.
// Stage schedule per iteration (tiles t=2i in buf0, t+1 in buf1):
//  ph1: A0(t+1)->buf1  ph2: A1(t+1)->buf1  ph3: B0(t+2)->buf0  ph4: B1(t+2)->buf0 [vmcnt4]
//  ph5: A0(t+2)->buf0  ph6: A1(t+2)->buf0  ph7: B0(t+3)->buf1  ph8: B1(t+3)->buf1 [vmcnt4]

#define AHT(KT, H) (aT + ((size_t)(KT) * 2 + (H)) * HTB)
#define BHT(KT, H) (bT + ((size_t)(KT) * 2 + (H)) * HTB)

#define ST(GP, LO) do {                                                      \
    const char* g_ = (GP);                                                   \
    GLD16(g_ + tid * 16,        lds + (LO) + tid * 16);                      \
    GLD16(g_ + 8192 + tid * 16, lds + (LO) + 8192 + tid * 16);               \
} while (0)

#define VM4 asm volatile("s_waitcnt vmcnt(4)" ::: "memory")
#define VM0 asm volatile("s_waitcnt vmcnt(0)" ::: "memory")
#define NOPS ((void)0)

#define PHASE(D, MB, BPH, STG, GATE) do {                                     \
    const char* ab_ = lds + (D) * 65536 + wm * 16384 + row128;                \
    bf16x8 a00 = *reinterpret_cast<const bf16x8*>(ab_ + (MB) * 2048 + cs0);   \
    bf16x8 a01 = *reinterpret_cast<const bf16x8*>(ab_ + (MB) * 2048 + cs1);   \
    bf16x8 a10 = *reinterpret_cast<const bf16x8*>(ab_ + ((MB)+1) * 2048 + cs0);\
    bf16x8 a11 = *reinterpret_cast<const bf16x8*>(ab_ + ((MB)+1) * 2048 + cs1);\
    if (BPH) {                                                                \
        const char* bb_ = lds + (D) * 65536 + 32768 + bsel + row128;          \
        _Pragma("unroll")                                                     \
        for (int j = 0; j < 4; ++j) {                                         \
            Pb0[j] = *reinterpret_cast<const bf16x8*>(bb_ + j * 2048 + cs0);  \
            Pb1[j] = *reinterpret_cast<const bf16x8*>(bb_ + j * 2048 + cs1);  \
        }                                                                     \
    }                                                                         \
    STG;                                                                      \
    if (BPH) asm volatile("s_waitcnt lgkmcnt(8)" ::: "memory");               \
    __builtin_amdgcn_sched_barrier(0);                                        \
    __builtin_amdgcn_s_barrier();                                             \
    asm volatile("s_waitcnt lgkmcnt(0)" ::: "memory");                        \
    __builtin_amdgcn_sched_barrier(0);                                        \
    __builtin_amdgcn_s_setprio(1);                                            \
    _Pragma("unroll")                                                         \
    for (int j = 0; j < 4; ++j) {                                             \
        acc[MB][j]     = __builtin_amdgcn_mfma_f32_16x16x32_bf16(a00, Pb0[j], acc[MB][j], 0, 0, 0);     \
        acc[MB][j]     = __builtin_amdgcn_mfma_f32_16x16x32_bf16(a01, Pb1[j], acc[MB][j], 0, 0, 0);     \
        acc[(MB)+1][j] = __builtin_amdgcn_mfma_f32_16x16x32_bf16(a10, Pb0[j], acc[(MB)+1][j], 0, 0, 0); \
        acc[(MB)+1][j] = __builtin_amdgcn_mfma_f32_16x16x32_bf16(a11, Pb1[j], acc[(MB)+1][j], 0, 0, 0); \
    }                                                                         \
    __builtin_amdgcn_s_setprio(0);                                            \
    GATE;                                                                     \
    __builtin_amdgcn_sched_barrier(0);                                        \
    __builtin_amdgcn_s_barrier();                                             \
} while (0)

__global__ __launch_bounds__(512, 1)
void k_gemm(const char* __restrict__ hws, const char* __restrict__ w2ws,
            float* __restrict__ out)
{
    __shared__ __align__(16) char lds[131072];

    const int tid  = threadIdx.x;
    const int lane = tid & 63;
    const int wave = tid >> 6;
    const int wm = wave >> 2;        // 0..1  (m-half)
    const int wn = wave & 3;         // 0..3  (n-quarter)
    const int mt = blockIdx.x;       // 0..63
    const int nt = blockIdx.y;       // 0..3

    const char* aT = hws  + (size_t)mt * NKT * 2 * HTB;
    const char* bT = w2ws + (size_t)nt * NKT * 2 * HTB;

    const int l16    = lane & 15;
    const int row128 = l16 * 128;
    const int cs0    = ((lane >> 4) * 16) ^ ((l16 & 7) << 4);
    const int cs1    = cs0 ^ 64;
    const int bsel   = (wn >> 1) * 16384 + (wn & 1) * 8192;

    bf16x8 Pb0[4], Pb1[4];
    f32x4 acc[8][4];
    #pragma unroll
    for (int i = 0; i < 8; ++i)
        #pragma unroll
        for (int j = 0; j < 4; ++j)
            acc[i][j] = {0.f, 0.f, 0.f, 0.f};

    // prologue: tile0 (4 halves) + B halves of tile1; gate all but B(1)
    ST(AHT(0, 0), 0);
    ST(AHT(0, 1), 16384);
    ST(BHT(0, 0), 32768);
    ST(BHT(0, 1), 49152);
    ST(BHT(1, 0), 98304);
    ST(BHT(1, 1), 114688);
    VM4;
    __builtin_amdgcn_sched_barrier(0);
    __builtin_amdgcn_s_barrier();
    __builtin_amdgcn_sched_barrier(0);

    #pragma unroll 1
    for (int it = 0; it < 31; ++it) {
        const int t = 2 * it;
        PHASE(0, 0, 1, ST(AHT(t + 1, 0), 65536),         NOPS);
        PHASE(0, 2, 0, ST(AHT(t + 1, 1), 81920),         NOPS);
        PHASE(0, 4, 0, ST(BHT(t + 2, 0), 32768),         NOPS);
        PHASE(0, 6, 0, ST(BHT(t + 2, 1), 49152),         VM4);
        PHASE(1, 0, 1, ST(AHT(t + 2, 0), 0),             NOPS);
        PHASE(1, 2, 0, ST(AHT(t + 2, 1), 16384),         NOPS);
        PHASE(1, 4, 0, ST(BHT(t + 3, 0), 98304),         NOPS);
        PHASE(1, 6, 0, ST(BHT(t + 3, 1), 114688),        VM4);
    }
    // last iteration: t = 62, 63; only A(63) still needs staging
    PHASE(0, 0, 1, ST(AHT(63, 0), 65536),  NOPS);
    PHASE(0, 2, 0, ST(AHT(63, 1), 81920),  NOPS);
    PHASE(0, 4, 0, NOPS,                   NOPS);
    PHASE(0, 6, 0, NOPS,                   VM0);
    PHASE(1, 0, 1, NOPS, NOPS);
    PHASE(1, 2, 0, NOPS, NOPS);
    PHASE(1, 4, 0, NOPS, NOPS);
    PHASE(1, 6, 0, NOPS, NOPS);

    const int orow0 = mt * 256 + wm * 128 + (lane >> 4) * 4;
    const int ocol0 = nt * 256 + wn * 64 + l16;
    #pragma unroll
    for (int i = 0; i < 8; ++i)
        #pragma unroll
        for (int j = 0; j < 4; ++j)
            #pragma unroll
            for (int jj = 0; jj < 4; ++jj)
                out[(size_t)(orow0 + i * 16 + jj) * N_TOT + (ocol0 + j * 16)] = acc[i][j][jj];
}

// ---------------- fallback: fused single kernel (ws too small) ----------------
__global__ __launch_bounds__(256, 3)
void qffn_fused(const float* __restrict__ x, const float* __restrict__ theta,
                const float* __restrict__ W1, const float* __restrict__ W2,
                float* __restrict__ out)
{
    __shared__ __align__(16) unsigned short sA[128 * 64];
    __shared__ __align__(16) unsigned short sB[128 * 64];

    const int tid  = threadIdx.x;
    const int lane = tid & 63;
    const int wave = tid >> 6;
    const int m0 = blockIdx.x * 128;
    const int n0 = blockIdx.y * 128;

    const int arow = tid & 127;
    float zc[8];
    {
        const float* xp = x + (size_t)(m0 + arow) * 1024;
        f32x4 x0 = *reinterpret_cast<const f32x4*>(xp);
        f32x4 x1 = *reinterpret_cast<const f32x4*>(xp + 4);
        #pragma unroll
        for (int q = 0; q < 4; ++q) {
            zc[q]     = cosf(x0[q]) * cosf(theta[q]);
            zc[q + 4] = cosf(x1[q]) * cosf(theta[q + 4]);
        }
    }

    f32x4 acc[4][4];
    #pragma unroll
    for (int i = 0; i < 4; ++i)
        #pragma unroll
        for (int j = 0; j < 4; ++j)
            acc[i][j] = {0.f, 0.f, 0.f, 0.f};

    const int wr  = (wave >> 1) * 64;
    const int wc  = (wave & 1) * 64;
    const int l16 = lane & 15;
    const int lk8 = (lane >> 4) * 8;

    for (int k0 = 0; k0 < K_TOT; k0 += 64) {
        #pragma unroll
        for (int g = 0; g < 4; ++g) {
            const int cg  = (tid >> 7) + 2 * g;
            const int cgu = __builtin_amdgcn_readfirstlane(cg);
            const float* w1p = W1 + (size_t)(k0 + cgu * 8) * 8;
            i32x4 pk;
            #pragma unroll
            for (int p = 0; p < 4; ++p) {
                float h0 = 0.f, h1 = 0.f;
                #pragma unroll
                for (int q = 0; q < 8; ++q) {
                    h0 = fmaf(zc[q], w1p[(2 * p) * 8 + q], h0);
                    h1 = fmaf(zc[q], w1p[(2 * p + 1) * 8 + q], h1);
                }
                pk[p] = (int)(((unsigned)f2bf(fmaxf(h0, 0.f))) |
                              (((unsigned)f2bf(fmaxf(h1, 0.f))) << 16));
            }
            const int off = (arow * 64 + cg * 8) ^ ((arow & 7) << 3);
            *reinterpret_cast<i32x4*>(&sA[off]) = pk;
        }
        {
            const int fi = tid & 15;
            const int rb = tid >> 4;
            #pragma unroll
            for (int r = 0; r < 8; ++r) {
                const int row = rb + r * 16;
                f32x4 v = *(reinterpret_cast<const f32x4*>(W2 + (size_t)(n0 + row) * K_TOT + k0) + fi);
                unsigned p0 = (unsigned)f2bf(v[0]) | ((unsigned)f2bf(v[1]) << 16);
                unsigned p1 = (unsigned)f2bf(v[2]) | ((unsigned)f2bf(v[3]) << 16);
                const int off = (row * 64 + fi * 4) ^ ((row & 7) << 3);
                *reinterpret_cast<unsigned*>(&sB[off])     = p0;
                *reinterpret_cast<unsigned*>(&sB[off + 2]) = p1;
            }
        }
        __syncthreads();

        #pragma unroll
        for (int s = 0; s < 2; ++s) {
            bf16x8 af[4], bfr[4];
            #pragma unroll
            for (int i = 0; i < 4; ++i) {
                const int row = wr + i * 16 + l16;
                const int off = (row * 64 + s * 32 + lk8) ^ ((row & 7) << 3);
                af[i] = *reinterpret_cast<const bf16x8*>(&sA[off]);
            }
            #pragma unroll
            for (int j = 0; j < 4; ++j) {
                const int row = wc + j * 16 + l16;
                const int off = (row * 64 + s * 32 + lk8) ^ ((row & 7) << 3);
                bfr[j] = *reinterpret_cast<const bf16x8*>(&sB[off]);
            }
            #pragma unroll
            for (int i = 0; i < 4; ++i)
                #pragma unroll
                for (int j = 0; j < 4; ++j)
                    acc[i][j] = __builtin_amdgcn_mfma_f32_16x16x32_bf16(af[i], bfr[j], acc[i][j], 0, 0, 0);
        }
        __syncthreads();
    }

    const int orow0 = m0 + wr + (lane >> 4) * 4;
    const int ocol0 = n0 + wc + l16;
    #pragma unroll
    for (int i = 0; i < 4; ++i)
        #pragma unroll
        for (int j = 0; j < 4; ++j)
            #pragma unroll
            for (int jj = 0; jj < 4; ++jj)
                out[(size_t)(orow0 + i * 16 + jj) * N_TOT + (ocol0 + j * 16)] = acc[i][j][jj];
}

extern "C" void kernel_launch(void* const* d_in, const int* in_sizes, int n_in,
                              void* d_out, int out_size, void* d_ws, size_t ws_size,
                              hipStream_t stream) {
    const float* x     = (const float*)d_in[0];
    const float* theta = (const float*)d_in[1];
    const float* W1    = (const float*)d_in[2];
    const float* W2    = (const float*)d_in[3];
    float* out = (float*)d_out;

    if (ws_size >= WS_NEED) {
        char* hws  = (char*)d_ws;
        char* w2ws = (char*)d_ws + H_BYTES;

        k_prep<<<dim3(4096), dim3(256), 0, stream>>>(x, theta, W1, W2, hws, w2ws);
        k_gemm<<<dim3(M_TOT / 256, N_TOT / 256), dim3(512), 0, stream>>>(hws, w2ws, out);
    } else {
        qffn_fused<<<dim3(M_TOT / 128, N_TOT / 128), dim3(256), 0, stream>>>(x, theta, W1, W2, out);
    }
}